// Round 7
// baseline (73.472 us; speedup 1.0000x reference)
//
#include <hip/hip_runtime.h>
#include <cstdint>

#define IN_FEAT 256
#define OUT_FEAT 64

constexpr int GEMM_GRID = 521;      // 1563 tiles = 521 blocks x 3 tiles exactly

typedef __attribute__((ext_vector_type(4))) float f32x4;
typedef __attribute__((ext_vector_type(8))) _Float16 f16x8;

union HF8 { _Float16 h[8]; f16x8 v; };

// ---------------------------------------------------------------------------
// Kernel 1 (persistent, pipelined): proj(fp16) = feat @ W via
// mfma_f32_16x16x32_f16, PLUS zeroing of `out` (folded memset).
// W packed once per block into B-fragment LDS layout (coalesced reads).
// Each block owns tiles t = blockIdx, +521, +1042 (3 iterations).
// Pipeline per iteration: [cvt fa->af] -> [issue next tile's 16 feat loads]
// -> [32 MFMA from af + LDS] -> [store proj, zero out rows]. The next tile's
// loads are in flight during MFMA+store, so feat streams at HBM rate.
// ---------------------------------------------------------------------------
__global__ __launch_bounds__(256) void gemm_proj_mfma(
    const float* __restrict__ feat, const float* __restrict__ W,
    _Float16* __restrict__ projh, float* __restrict__ out, int n_rows)
{
    __shared__ _Float16 sWh[8 * 4 * 64 * 8];   // 16384 fp16 = 32 KB

    // W -> fp16, packed to B-frag layout (coalesced: 256 consecutive floats
    // per j-step across the block; L2-hot after first blocks).
    {
        const int c   = threadIdx.x & 63;
        const int kg0 = threadIdx.x >> 6;
        #pragma unroll
        for (int it = 0; it < 8; ++it) {
            const int kg = it * 4 + kg0;         // k = kg*8 + j
            HF8 tmp;
            #pragma unroll
            for (int j = 0; j < 8; ++j)
                tmp.h[j] = (_Float16)W[(kg * 8 + j) * OUT_FEAT + c];
            const int ks = kg >> 2;
            const int l  = (kg & 3) * 16 + (c & 15);
            const int ct = c >> 4;
            *reinterpret_cast<f16x8*>(&sWh[((ks * 4 + ct) * 64 + l) * 8]) = tmp.v;
        }
    }
    __syncthreads();

    const int lane = threadIdx.x & 63;
    const int wave = threadIdx.x >> 6;
    const int kgrp = lane >> 4;            // 0..3
    const int ntiles = (n_rows + 63) >> 6;

    int t = blockIdx.x;
    if (t >= ntiles) return;

    f32x4 fa[16];
    {   // initial tile's feat loads (16 dwordx4 in flight)
        int ar = t * 64 + wave * 16 + (lane & 15);
        if (ar >= n_rows) ar = n_rows - 1;
        const float* fp = feat + (size_t)ar * IN_FEAT + kgrp * 8;
        #pragma unroll
        for (int ks = 0; ks < 8; ++ks) {
            fa[2 * ks]     = *reinterpret_cast<const f32x4*>(fp + ks * 32);
            fa[2 * ks + 1] = *reinterpret_cast<const f32x4*>(fp + ks * 32 + 4);
        }
    }

    while (true) {
        // Convert fa -> A-fragments (frees fa for the next tile's loads).
        HF8 af[8];
        #pragma unroll
        for (int ks = 0; ks < 8; ++ks) {
            #pragma unroll
            for (int h = 0; h < 2; ++h) {
                const f32x4 v = fa[2 * ks + h];
                #pragma unroll
                for (int j = 0; j < 4; ++j)
                    af[ks].h[h * 4 + j] = (_Float16)v[j];
            }
        }

        // Prefetch next tile's feat while we do MFMA + stores.
        const int tn = t + GEMM_GRID;
        if (tn < ntiles) {
            int ar = tn * 64 + wave * 16 + (lane & 15);
            if (ar >= n_rows) ar = n_rows - 1;
            const float* fp = feat + (size_t)ar * IN_FEAT + kgrp * 8;
            #pragma unroll
            for (int ks = 0; ks < 8; ++ks) {
                fa[2 * ks]     = *reinterpret_cast<const f32x4*>(fp + ks * 32);
                fa[2 * ks + 1] = *reinterpret_cast<const f32x4*>(fp + ks * 32 + 4);
            }
        }

        f32x4 acc[4];
        #pragma unroll
        for (int ct = 0; ct < 4; ++ct) acc[ct] = f32x4{0.f, 0.f, 0.f, 0.f};

        #pragma unroll
        for (int ks = 0; ks < 8; ++ks) {
            #pragma unroll
            for (int ct = 0; ct < 4; ++ct) {
                HF8 B;
                B.v = *reinterpret_cast<const f16x8*>(
                    &sWh[((ks * 4 + ct) * 64 + lane) * 8]);
                acc[ct] = __builtin_amdgcn_mfma_f32_16x16x32_f16(
                    af[ks].v, B.v, acc[ct], 0, 0, 0);
            }
        }

        const int row0 = t * 64 + wave * 16;
        #pragma unroll
        for (int r = 0; r < 4; ++r) {
            const int row = row0 + kgrp * 4 + r;
            if (row < n_rows) {
                #pragma unroll
                for (int ct = 0; ct < 4; ++ct)
                    projh[(size_t)row * OUT_FEAT + ct * 16 + (lane & 15)] =
                        (_Float16)acc[ct][r];
            }
        }
        // Zero this wave's 16 out-rows (folded memset; 4x dwordx4 per lane).
        #pragma unroll
        for (int i = 0; i < 4; ++i) {
            const int row = row0 + i * 4 + (lane >> 4);
            if (row < n_rows)
                *reinterpret_cast<f32x4*>(
                    out + (size_t)row0 * OUT_FEAT + i * 256 + lane * 4) =
                    f32x4{0.f, 0.f, 0.f, 0.f};
        }

        if (tn >= ntiles) break;
        t = tn;
    }
}

// ---------------------------------------------------------------------------
// Kernel 2: out[row] += val * proj[col] over sorted-by-row COO edges.
// One wave owns 128 contiguous edges (two 64-edge chunks A,B); lane = col.
// All 128 gathers issue back-to-back (static readlane indices -> SGPR cols),
// then the two segmented accumulate/flush phases run sequentially.
// Interior segments (start AND end inside a chunk) are exclusively owned
// (rows sorted) -> plain store onto the gemm-zeroed out; chunk-boundary
// flushes (first + final of each chunk) use atomicAdd.
// ---------------------------------------------------------------------------
__global__ __launch_bounds__(256) void gather_scatter(
    const _Float16* __restrict__ projh, const int* __restrict__ rows,
    const int* __restrict__ cols, const float* __restrict__ vals,
    float* __restrict__ out, int n_edges)
{
    const int lane = threadIdx.x & 63;
    const long wid = (long)((blockIdx.x * 256 + threadIdx.x) >> 6);
    const long e0 = wid * 128;
    if (e0 >= n_edges) return;

    // Coalesced metadata preload for both chunks (clamped tail, v=0).
    const long a0 = e0, b0 = e0 + 64;
    const long eA = (a0 + lane < n_edges) ? (a0 + lane) : (n_edges - 1);
    const long eB = (b0 + lane < n_edges) ? (b0 + lane) : (n_edges - 1);
    const int rA = rows[eA], cA = cols[eA];
    const int rB = rows[eB], cB = cols[eB];
    const int vA = (a0 + lane < n_edges) ? __builtin_bit_cast(int, vals[eA]) : 0;
    const int vB = (b0 + lane < n_edges) ? __builtin_bit_cast(int, vals[eB]) : 0;

    // Phase 1: issue all 128 gathers (full MLP).
    _Float16 pA[64], pB[64];
    #pragma unroll
    for (int i = 0; i < 64; ++i) {
        const int c = __builtin_amdgcn_readlane(cA, i);    // SGPR
        pA[i] = projh[(size_t)c * OUT_FEAT + lane];
    }
    #pragma unroll
    for (int i = 0; i < 64; ++i) {
        const int c = __builtin_amdgcn_readlane(cB, i);    // SGPR
        pB[i] = projh[(size_t)c * OUT_FEAT + lane];
    }

    // Phase 2A: segmented accumulate + flush for chunk A.
    {
        float acc = 0.f;
        int cur = __builtin_amdgcn_readlane(rA, 0);
        bool first_seg = true;                              // uniform
        #pragma unroll
        for (int i = 0; i < 64; ++i) {
            const int   r = __builtin_amdgcn_readlane(rA, i);
            const float v = __builtin_bit_cast(float, __builtin_amdgcn_readlane(vA, i));
            if (r != cur) {                                 // scalar, uniform
                float* dst = out + (size_t)cur * OUT_FEAT + lane;
                if (first_seg) atomicAdd(dst, acc);         // may span waves
                else           *dst = acc;                  // exclusive row
                first_seg = false;
                acc = 0.f;
                cur = r;
            }
            acc = fmaf(v, (float)pA[i], acc);
        }
        atomicAdd(out + (size_t)cur * OUT_FEAT + lane, acc); // boundary
    }
    // Phase 2B: chunk B.
    {
        float acc = 0.f;
        int cur = __builtin_amdgcn_readlane(rB, 0);
        bool first_seg = true;
        #pragma unroll
        for (int i = 0; i < 64; ++i) {
            const int   r = __builtin_amdgcn_readlane(rB, i);
            const float v = __builtin_bit_cast(float, __builtin_amdgcn_readlane(vB, i));
            if (r != cur) {
                float* dst = out + (size_t)cur * OUT_FEAT + lane;
                if (first_seg) atomicAdd(dst, acc);
                else           *dst = acc;
                first_seg = false;
                acc = 0.f;
                cur = r;
            }
            acc = fmaf(v, (float)pB[i], acc);
        }
        atomicAdd(out + (size_t)cur * OUT_FEAT + lane, acc);
    }
}

extern "C" void kernel_launch(void* const* d_in, const int* in_sizes, int n_in,
                              void* d_out, int out_size, void* d_ws, size_t ws_size,
                              hipStream_t stream)
{
    const float* feat     = (const float*)d_in[0];
    const float* weight   = (const float*)d_in[1];
    const int*   adj_rows = (const int*)d_in[2];
    const int*   adj_cols = (const int*)d_in[3];
    const float* adj_vals = (const float*)d_in[4];
    float*       out      = (float*)d_out;
    _Float16*    projh    = (_Float16*)d_ws;   // n_nodes*64*2 = 12.8 MB

    const int n_nodes = in_sizes[0] / IN_FEAT;   // 100000
    const int n_edges = in_sizes[2];             // 1600000

    const int ntiles = (n_nodes + 63) / 64;
    const int gemm_blocks = (ntiles < GEMM_GRID) ? ntiles : GEMM_GRID;
    gemm_proj_mfma<<<gemm_blocks, 256, 0, stream>>>(feat, weight, projh, out,
                                                    n_nodes);

    const int waves  = (n_edges + 127) / 128;
    const int blocks = (waves + 3) / 4;
    gather_scatter<<<blocks, 256, 0, stream>>>(projh, adj_rows, adj_cols,
                                               adj_vals, out, n_edges);
}

// Round 8
// 61.530 us; speedup vs baseline: 1.1941x; 1.1941x over previous
//
#include <hip/hip_runtime.h>
#include <cstdint>

#define IN_FEAT 256
#define OUT_FEAT 64

constexpr int EPW = 64;             // edges per wave in scatter (1 per lane)

typedef __attribute__((ext_vector_type(4))) float f32x4;
typedef __attribute__((ext_vector_type(8))) _Float16 f16x8;

union HF8 { _Float16 h[8]; f16x8 v; };

// ---------------------------------------------------------------------------
// Kernel 1: proj(fp16) = feat @ W via mfma_f32_16x16x32_f16, plus zeroing of
// `out` (folded memset, coalesced 1 KB per wave).
// Key fix this round: a sched_barrier(0) after the 16-deep feat load batch.
// Round-4 counters showed VGPR=44 (< the 64 fa[] needs) => the compiler was
// sinking loads to their converts, serializing them (~3.3 TB/s). Pinning the
// batch keeps all 16 dwordx4 in flight under the W-pack prologue.
// W staged in LDS pre-packed into B-fragment layout:
//   sWh[((ks*4+ct)*64 + l)*8 + j] = f16(W[ks*32 + (l>>4)*8 + j][ct*16+(l&15)])
// Block = 256 thr = 4 waves, each wave one 16-row x 64-col tile.
// ---------------------------------------------------------------------------
__global__ __launch_bounds__(256) void gemm_proj_mfma(
    const float* __restrict__ feat, const float* __restrict__ W,
    _Float16* __restrict__ projh, float* __restrict__ out, int n_rows)
{
    __shared__ _Float16 sWh[8 * 4 * 64 * 8];   // 16384 fp16 = 32 KB

    const int lane = threadIdx.x & 63;
    const int wave = threadIdx.x >> 6;
    const int row0 = blockIdx.x * 64 + wave * 16;
    const int kgrp = lane >> 4;            // 0..3
    int ar = row0 + (lane & 15);           // this lane's A row
    if (ar >= n_rows) ar = n_rows - 1;     // clamp; results discarded on store

    // Phase A: issue the full feat row-chunk (16 dwordx4) and PIN the batch.
    f32x4 fa[16];
    const float* fp = feat + (size_t)ar * IN_FEAT + kgrp * 8;
    #pragma unroll
    for (int ks = 0; ks < 8; ++ks) {
        fa[2 * ks]     = *reinterpret_cast<const f32x4*>(fp + ks * 32);
        fa[2 * ks + 1] = *reinterpret_cast<const f32x4*>(fp + ks * 32 + 4);
    }
    __builtin_amdgcn_sched_barrier(0);     // keep all 16 loads issued here

    // Phase B: W -> fp16, packed to B-frag layout (coalesced, L2-hot).
    {
        const int c   = threadIdx.x & 63;        // W column (coalesced axis)
        const int kg0 = threadIdx.x >> 6;        // k-group 0..3 within iter
        #pragma unroll
        for (int it = 0; it < 8; ++it) {
            const int kg = it * 4 + kg0;         // k-group 0..31 (k = kg*8+j)
            HF8 tmp;
            #pragma unroll
            for (int j = 0; j < 8; ++j)
                tmp.h[j] = (_Float16)W[(kg * 8 + j) * OUT_FEAT + c];
            const int ks = kg >> 2;
            const int l  = (kg & 3) * 16 + (c & 15);
            const int ct = c >> 4;
            *reinterpret_cast<f16x8*>(&sWh[((ks * 4 + ct) * 64 + l) * 8]) = tmp.v;
        }
    }
    __syncthreads();
    if (row0 >= n_rows) return;            // after barrier: uniform participation

    f32x4 acc[4];
    #pragma unroll
    for (int ct = 0; ct < 4; ++ct) acc[ct] = f32x4{0.f, 0.f, 0.f, 0.f};

    #pragma unroll
    for (int ks = 0; ks < 8; ++ks) {
        HF8 A;
        #pragma unroll
        for (int h = 0; h < 2; ++h) {
            const f32x4 v = fa[2 * ks + h];
            #pragma unroll
            for (int j = 0; j < 4; ++j)
                A.h[h * 4 + j] = (_Float16)v[j];   // compiler packs: v_cvt_pk
        }
        #pragma unroll
        for (int ct = 0; ct < 4; ++ct) {
            HF8 B;
            B.v = *reinterpret_cast<const f16x8*>(
                &sWh[((ks * 4 + ct) * 64 + lane) * 8]);
            acc[ct] = __builtin_amdgcn_mfma_f32_16x16x32_f16(A.v, B.v, acc[ct], 0, 0, 0);
        }
    }

    #pragma unroll
    for (int r = 0; r < 4; ++r) {
        const int row = row0 + kgrp * 4 + r;
        if (row < n_rows) {
            #pragma unroll
            for (int ct = 0; ct < 4; ++ct)
                projh[(size_t)row * OUT_FEAT + ct * 16 + (lane & 15)] =
                    (_Float16)acc[ct][r];
        }
    }

    // Folded memset: zero this wave's 16 out-rows (4 coalesced 256B bursts).
    #pragma unroll
    for (int i = 0; i < 4; ++i) {
        const int row = row0 + i * 4 + (lane >> 4);
        if (row < n_rows)
            *reinterpret_cast<f32x4*>(
                out + (size_t)row * OUT_FEAT + (lane & 15) * 4) =
                f32x4{0.f, 0.f, 0.f, 0.f};
    }
}

// ---------------------------------------------------------------------------
// Kernel 2: out[row] += val * proj[col]  over sorted-by-row COO edges.
// One wave owns 64 contiguous edges; lane = feature column.
// Phase 1: coalesced metadata preload, then fully static-unrolled gather of
// all 64 fp16 proj rows into p[64] (compile-time readlane -> SGPR col ->
// 64 independent loads). sched_barrier(0) pins the batch (prevents the
// compiler sinking each load to its fma, which would serialize latency).
// Phase 2: segmented register accumulation with SGPR row compares. Interior
// segments are exclusively owned (rows sorted) -> plain store onto the
// gemm-zeroed out; first + final flush use atomicAdd.
// ---------------------------------------------------------------------------
__global__ __launch_bounds__(256) void gather_scatter(
    const _Float16* __restrict__ projh, const int* __restrict__ rows,
    const int* __restrict__ cols, const float* __restrict__ vals,
    float* __restrict__ out, int n_edges)
{
    const int lane = threadIdx.x & 63;
    const long wid = (long)((blockIdx.x * 256 + threadIdx.x) >> 6);
    const long e0 = wid * EPW;
    if (e0 >= n_edges) return;

    const long ee = (e0 + lane < n_edges) ? (e0 + lane) : (n_edges - 1);
    const int r_v = rows[ee];
    const int c_v = cols[ee];
    const int v_bits = (e0 + lane < n_edges)
                         ? __builtin_bit_cast(int, vals[ee]) : 0;

    // Phase 1: issue all 64 gathers, pinned as a batch.
    _Float16 p[EPW];
    #pragma unroll
    for (int i = 0; i < EPW; ++i) {
        const int c = __builtin_amdgcn_readlane(c_v, i);   // SGPR
        p[i] = projh[(size_t)c * OUT_FEAT + lane];
    }
    __builtin_amdgcn_sched_barrier(0);

    // Phase 2: segmented accumulate + flush.
    float acc = 0.f;
    int cur = __builtin_amdgcn_readlane(r_v, 0);
    bool first_seg = true;                                  // uniform
    #pragma unroll
    for (int i = 0; i < EPW; ++i) {
        const int   r = __builtin_amdgcn_readlane(r_v, i);  // SGPR
        const float v = __builtin_bit_cast(float, __builtin_amdgcn_readlane(v_bits, i));
        if (r != cur) {                                     // scalar, uniform
            float* dst = out + (size_t)cur * OUT_FEAT + lane;
            if (first_seg) atomicAdd(dst, acc);             // may span waves
            else           *dst = acc;                      // exclusive row
            first_seg = false;
            acc = 0.f;
            cur = r;
        }
        acc = fmaf(v, (float)p[i], acc);
    }
    atomicAdd(out + (size_t)cur * OUT_FEAT + lane, acc);    // may span waves
}

extern "C" void kernel_launch(void* const* d_in, const int* in_sizes, int n_in,
                              void* d_out, int out_size, void* d_ws, size_t ws_size,
                              hipStream_t stream)
{
    const float* feat     = (const float*)d_in[0];
    const float* weight   = (const float*)d_in[1];
    const int*   adj_rows = (const int*)d_in[2];
    const int*   adj_cols = (const int*)d_in[3];
    const float* adj_vals = (const float*)d_in[4];
    float*       out      = (float*)d_out;
    _Float16*    projh    = (_Float16*)d_ws;   // n_nodes*64*2 = 12.8 MB

    const int n_nodes = in_sizes[0] / IN_FEAT;   // 100000
    const int n_edges = in_sizes[2];             // 1600000

    const int gemm_blocks = (n_nodes + 63) / 64;
    gemm_proj_mfma<<<gemm_blocks, 256, 0, stream>>>(feat, weight, projh, out,
                                                    n_nodes);

    const int waves  = (n_edges + EPW - 1) / EPW;
    const int blocks = (waves + 3) / 4;
    gather_scatter<<<blocks, 256, 0, stream>>>(projh, adj_rows, adj_cols,
                                               adj_vals, out, n_edges);
}